// Round 1
// baseline (223.247 us; speedup 1.0000x reference)
//
#include <hip/hip_runtime.h>
#include <math.h>

#define KCOMP 16
#define CHW 32768  // C*H*W = 8*64*64

__global__ void init_sldj_kernel(const float* __restrict__ sldj,
                                 float* __restrict__ out_sldj, int B) {
    int i = blockIdx.x * blockDim.x + threadIdx.x;
    if (i < B) out_sldj[i] = sldj[i];
}

__global__ __launch_bounds__(256) void coupling_kernel(
    const float* __restrict__ x_change, const float* __restrict__ x_id,
    const float* __restrict__ a, const float* __restrict__ b,
    const float* __restrict__ pi, const float* __restrict__ mu,
    const float* __restrict__ s, float* __restrict__ out, int N) {
    const int i = blockIdx.x * blockDim.x + threadIdx.x;
    float ldj_term = 0.0f;
    if (i < N) {
        const float x = x_change[i];

        // ---- load pi/mu/s (16 floats each, contiguous per element) ----
        float p[KCOMP], m[KCOMP], sv[KCOMP];
        const size_t base = (size_t)i * KCOMP;
        const float4* pv = (const float4*)(pi + base);
        const float4* mv = (const float4*)(mu + base);
        const float4* svv = (const float4*)(s + base);
#pragma unroll
        for (int c = 0; c < 4; ++c) {
            float4 t0 = pv[c];
            p[4 * c + 0] = t0.x; p[4 * c + 1] = t0.y; p[4 * c + 2] = t0.z; p[4 * c + 3] = t0.w;
            float4 t1 = mv[c];
            m[4 * c + 0] = t1.x; m[4 * c + 1] = t1.y; m[4 * c + 2] = t1.z; m[4 * c + 3] = t1.w;
            float4 t2 = svv[c];
            sv[4 * c + 0] = t2.x; sv[4 * c + 1] = t2.y; sv[4 * c + 2] = t2.z; sv[4 * c + 3] = t2.w;
        }

        // ---- log_softmax(pi) denominator ----
        float pmax = p[0];
#pragma unroll
        for (int k = 1; k < KCOMP; ++k) pmax = fmaxf(pmax, p[k]);
        float psum = 0.0f;
#pragma unroll
        for (int k = 0; k < KCOMP; ++k) psum += __expf(p[k] - pmax);
        const float lse_pi = pmax + __logf(psum);

        // ---- per-component terms ----
        float t[KCOMP], q[KCOMP];
        float mt = -1e30f, mq = -1e30f;
#pragma unroll
        for (int k = 0; k < KCOMP; ++k) {
            const float lp = p[k] - lse_pi;              // log_softmax(pi)_k
            const float sk = sv[k];
            const float z = (x - m[k]) * __expf(-sk);
            const float az = fabsf(z);
            const float l1 = __logf(1.0f + __expf(-az)); // log1p(exp(-|z|))
            const float ls = fminf(z, 0.0f) - l1;        // log_sigmoid(z)
            const float sp = fmaxf(z, 0.0f) + l1;        // softplus(z)
            const float logp = z - sk - 2.0f * sp;       // logistic log-pdf
            t[k] = lp + ls;
            q[k] = lp + logp;
            mt = fmaxf(mt, t[k]);
            mq = fmaxf(mq, q[k]);
        }
        float st = 0.0f, sq = 0.0f;
#pragma unroll
        for (int k = 0; k < KCOMP; ++k) {
            st += __expf(t[k] - mt);
            sq += __expf(q[k] - mq);
        }
        const float log_cdf = mt + __logf(st);
        const float logistic_ldj = mq + __logf(sq);

        // ---- sigmoid-inverse with log-det ----
        float one_m_u = -expm1f(log_cdf);                // 1 - exp(log_cdf), accurate
        one_m_u = fmaxf(one_m_u, 1e-30f);                // NaN guard (never hit for real data)
        const float l1mu = __logf(one_m_u);              // log(1-u)
        const float outv = log_cdf - l1mu;
        const float scale_ldj = -log_cdf - l1mu;

        const float av = a[i];
        const float bv = b[i];
        out[i] = (outv + bv) * __expf(av);
        out[(size_t)N + i] = x_id[i];                    // identity passthrough
        ldj_term = logistic_ldj + scale_ldj + av;
    }

    // ---- block reduction of ldj_term; block lies within one batch ----
    float v = ldj_term;
#pragma unroll
    for (int off = 32; off > 0; off >>= 1) v += __shfl_down(v, off);
    __shared__ float ws[4];
    const int lane = threadIdx.x & 63;
    const int wid = threadIdx.x >> 6;
    if (lane == 0) ws[wid] = v;
    __syncthreads();
    if (threadIdx.x == 0) {
        const float tot = ws[0] + ws[1] + ws[2] + ws[3];
        const int batch = (blockIdx.x * blockDim.x) / CHW;
        atomicAdd(out + 2 * (size_t)N + batch, tot);
    }
}

extern "C" void kernel_launch(void* const* d_in, const int* in_sizes, int n_in,
                              void* d_out, int out_size, void* d_ws, size_t ws_size,
                              hipStream_t stream) {
    const float* x_change = (const float*)d_in[0];
    const float* x_id     = (const float*)d_in[1];
    const float* sldj     = (const float*)d_in[2];
    const float* a        = (const float*)d_in[3];
    const float* b        = (const float*)d_in[4];
    const float* pi       = (const float*)d_in[5];
    const float* mu       = (const float*)d_in[6];
    const float* s        = (const float*)d_in[7];
    float* out = (float*)d_out;

    const int N = in_sizes[0];   // B*C*H*W
    const int B = in_sizes[2];

    // Seed sldj output region (harness poisons d_out before every launch),
    // then the main kernel atomically accumulates into it (stream-ordered).
    init_sldj_kernel<<<1, 64, 0, stream>>>(sldj, out + 2 * (size_t)N, B);

    const int block = 256;
    const int grid = (N + block - 1) / block;
    coupling_kernel<<<grid, block, 0, stream>>>(x_change, x_id, a, b, pi, mu, s, out, N);
}